// Round 4
// baseline (147.703 us; speedup 1.0000x reference)
//
#include <hip/hip_runtime.h>
#include <cstdint>

#define EPS 1e-5f

// ============ K1: per-plane row sums and col sums (2048 x 256) ============
__global__ __launch_bounds__(256) void k1_sums(const float* __restrict__ x,
                                               float* __restrict__ rowsum,
                                               float* __restrict__ colsum) {
    int p = blockIdx.x;
    int t = threadIdx.x;
    const float4* xp = (const float4*)(x + (size_t)p * 16384);
    float4 csum = {0.f, 0.f, 0.f, 0.f};
    for (int i = 0; i < 16; ++i) {
        float4 v = xp[i * 256 + t];
        csum.x += v.x; csum.y += v.y; csum.z += v.z; csum.w += v.w;
        float rs = v.x + v.y + v.z + v.w;
        for (int m = 16; m; m >>= 1) rs += __shfl_xor(rs, m);
        if ((t & 31) == 0) rowsum[p * 128 + i * 8 + (t >> 5)] = rs;
    }
    __shared__ float4 red[256];
    red[t] = csum;
    __syncthreads();
    if (t < 32) {
        float4 s = red[t];
        for (int j = 1; j < 8; ++j) {
            float4 v = red[j * 32 + t];
            s.x += v.x; s.y += v.y; s.z += v.z; s.w += v.w;
        }
        ((float4*)colsum)[p * 32 + t] = s;
    }
}

// ============ K2: per-bg gates + analytic x2-mean + x21 + stats + alpha/beta ============
__global__ __launch_bounds__(1024) void k2_mid(
    const float* __restrict__ x,
    const float* __restrict__ rowsum, const float* __restrict__ colsum,
    const float* __restrict__ w1, const float* __restrict__ b1,
    const float* __restrict__ w3, const float* __restrict__ b3,
    const float* __restrict__ gn_w, const float* __restrict__ gn_b,
    float* __restrict__ sh, float* __restrict__ sw,
    float* __restrict__ wt, float* __restrict__ alpha, float* __restrict__ beta)
{
    __shared__ float rs[1024], cs[1024], shl[1024], swl[1024];
    __shared__ float w1l[64], b1l[8], corn[32], S[8], Tm[72], m2[8], x11[8], x21l[8];
    __shared__ float ps[64], qs[64], bs[8];
    __shared__ float btl;
    const int bg = blockIdx.x;
    const int t  = threadIdx.x;
    const int sg = t >> 8, ts = t & 255;
    const size_t pbase = (size_t)(bg * 8) * 16384;

    rs[t] = rowsum[bg * 1024 + t];
    cs[t] = colsum[bg * 1024 + t];
    if (t < 64) w1l[t] = w1[t];
    if (t >= 64 && t < 72) b1l[t - 64] = b1[t - 64];
    if (t >= 128 && t < 136) {
        int i = t - 128;
        const float* xpp = x + pbase + (size_t)i * 16384;
        corn[i * 4 + 0] = xpp[0];
        corn[i * 4 + 1] = xpp[127];
        corn[i * 4 + 2] = xpp[127 * 128];
        corn[i * 4 + 3] = xpp[127 * 128 + 127];
    }
    if (t == 200) {   // x11 = softmax(gn_b)
        float mx = gn_b[0];
        for (int i = 1; i < 8; ++i) mx = fmaxf(mx, gn_b[i]);
        float e[8], s = 0.f;
        for (int i = 0; i < 8; ++i) { e[i] = __expf(gn_b[i] - mx); s += e[i]; }
        for (int i = 0; i < 8; ++i) x11[i] = e[i] / s;
    }
    __syncthreads();

    if (t == 300) {   // btilde (local per block -> no cross-block dependence)
        float a = 0.f;
        for (int o = 0; o < 8; ++o) a += x11[o] * b3[o];
        btl = a;
    }
    {   // gates: 8 o-channels x 128 positions
        int o = t >> 7, y = t & 127;
        const float inv128 = 1.f / 128.f;
        float ar = b1l[o], ac = ar;
        for (int i = 0; i < 8; ++i) {
            float w = w1l[o * 8 + i];
            ar += w * rs[i * 128 + y] * inv128;
            ac += w * cs[i * 128 + y] * inv128;
        }
        float sv = 1.f / (1.f + __expf(-ar));
        float wv = 1.f / (1.f + __expf(-ac));
        shl[o * 128 + y] = sv;  sh[(bg * 8 + o) * 128 + y] = sv;
        swl[o * 128 + y] = wv;  sw[(bg * 8 + o) * 128 + y] = wv;
    }
    if (t < 8) {
        float s = 0.f;
        for (int y = 0; y < 128; ++y) s += rs[t * 128 + y];
        S[t] = s;
    }
    __syncthreads();

    if (t < 72) {   // shifted-window sums for SAME zero padding
        int i = t / 9, ky = (t % 9) / 3, kx = t % 3;
        float v = S[i];
        if (ky == 0) v -= rs[i * 128 + 127]; else if (ky == 2) v -= rs[i * 128 + 0];
        if (kx == 0) v -= cs[i * 128 + 127]; else if (kx == 2) v -= cs[i * 128 + 0];
        if (ky == 0 && kx == 0) v += corn[i * 4 + 3];
        if (ky == 0 && kx == 2) v += corn[i * 4 + 2];
        if (ky == 2 && kx == 0) v += corn[i * 4 + 1];
        if (ky == 2 && kx == 2) v += corn[i * 4 + 0];
        Tm[t] = v;
    }
    __syncthreads();

    if (t < 8) {
        float acc = 0.f;
        for (int j = 0; j < 72; ++j) acc += w3[t * 72 + j] * Tm[j];
        m2[t] = b3[t] + acc * (1.f / 16384.f);
    }
    if (bg == 0 && t >= 128 && t < 200) {   // collapsed conv weights
        int j = t - 128;
        float a = 0.f;
        for (int o = 0; o < 8; ++o) a += x11[o] * w3[o * 72 + j];
        wt[j] = a;
    }
    __syncthreads();

    if (t == 0) {   // x21 = softmax(m2), kept in LDS
        float mx = m2[0];
        for (int i = 1; i < 8; ++i) mx = fmaxf(mx, m2[i]);
        float e[8], s = 0.f;
        for (int i = 0; i < 8; ++i) { e[i] = __expf(m2[i] - mx); s += e[i]; }
        for (int i = 0; i < 8; ++i) x21l[i] = e[i] / s;
    }
    __syncthreads();

    // stats: gated sum & sumsq per plane (x re-read, L3-hot)
    for (int half = 0; half < 2; ++half) {
        int pi = half * 4 + sg;
        const float4* xp = (const float4*)(x + pbase + (size_t)pi * 16384);
        float4 sw4 = ((const float4*)(swl + pi * 128))[ts & 31];
        float s = 0.f, q = 0.f;
        for (int i = 0; i < 16; ++i) {
            float4 v = xp[i * 256 + ts];
            float shv = shl[pi * 128 + i * 8 + (ts >> 5)];
            float g0 = v.x * shv * sw4.x;
            float g1 = v.y * shv * sw4.y;
            float g2 = v.z * shv * sw4.z;
            float g3 = v.w * shv * sw4.w;
            s += g0 + g1 + g2 + g3;
            q += g0 * g0 + g1 * g1 + g2 * g2 + g3 * g3;
        }
        for (int m = 16; m; m >>= 1) { s += __shfl_xor(s, m); q += __shfl_xor(q, m); }
        if ((ts & 31) == 0) {
            ps[pi * 8 + (ts >> 5)] = s;
            qs[pi * 8 + (ts >> 5)] = q;
        }
    }
    __syncthreads();
    if (t < 8) {
        float s = 0.f, q = 0.f;
        for (int j = 0; j < 8; ++j) { s += ps[t * 8 + j]; q += qs[t * 8 + j]; }
        float mu  = s * (1.f / 16384.f);
        float ex2 = q * (1.f / 16384.f);
        float var = ex2 - mu * mu;
        float inv = rsqrtf(var + EPS);
        float x21v = x21l[t];
        alpha[bg * 8 + t] = x21v * inv * gn_w[t];
        bs[t] = x21v * (gn_b[t] - mu * inv * gn_w[t]);
    }
    __syncthreads();
    if (t == 0) {
        float s = btl;
        for (int i = 0; i < 8; ++i) s += bs[i];
        beta[bg] = s;
    }
}

// ============ K3: collapsed conv + gating + sigmoid + output, no LDS tile ============
// 2048 blocks (8 per bg, 16 rows each), 256 threads, 2 rows/thread, loads direct from L2/L3.
__global__ __launch_bounds__(256) void k3_out(
    const float* __restrict__ x, const float* __restrict__ sh,
    const float* __restrict__ sw, const float* __restrict__ alpha,
    const float* __restrict__ beta, const float* __restrict__ wt,
    float* __restrict__ out)
{
    __shared__ float wtl[72], al[8], shl[128], swl[1024];
    __shared__ float betal;
    const int blk = blockIdx.x, bg = blk >> 3, r0 = (blk & 7) * 16;
    const int t = threadIdx.x, lane = t & 31, yg = t >> 5;
    const size_t pbase = (size_t)(bg * 8) * 16384;

    if (t < 72) wtl[t] = wt[t];
    if (t >= 72 && t < 80) al[t - 72] = alpha[bg * 8 + (t - 72)];
    if (t == 80) betal = beta[bg];
    if (t >= 96 && t < 224) {
        int j = t - 96;  // j>>4 = channel, j&15 = row within slab
        shl[j] = sh[(size_t)(bg * 8 + (j >> 4)) * 128 + r0 + (j & 15)];
    }
    ((float4*)swl)[t] = ((const float4*)sw)[(size_t)(bg * 8 + yg) * 32 + lane];
    __syncthreads();

    const int y0 = r0 + 2 * yg;
    const int x0 = lane * 4;
    float4 accA = {betal, betal, betal, betal};
    float4 accB = accA;
    const float4 z4 = {0.f, 0.f, 0.f, 0.f};

#pragma unroll
    for (int i = 0; i < 8; ++i) {
        const float* bp = x + pbase + (size_t)i * 16384 + x0;
        float4 v0 = (y0 - 1 >= 0)  ? *(const float4*)(bp + (y0 - 1) * 128) : z4;
        float4 v1 = *(const float4*)(bp + y0 * 128);
        float4 v2 = *(const float4*)(bp + (y0 + 1) * 128);
        float4 v3 = (y0 + 2 < 128) ? *(const float4*)(bp + (y0 + 2) * 128) : z4;

        float m0 = __shfl_up(v0.w, 1, 32); if (lane == 0) m0 = 0.f;
        float m1 = __shfl_up(v1.w, 1, 32); if (lane == 0) m1 = 0.f;
        float m2v = __shfl_up(v2.w, 1, 32); if (lane == 0) m2v = 0.f;
        float m3 = __shfl_up(v3.w, 1, 32); if (lane == 0) m3 = 0.f;
        float p0 = __shfl_down(v0.x, 1, 32); if (lane == 31) p0 = 0.f;
        float p1 = __shfl_down(v1.x, 1, 32); if (lane == 31) p1 = 0.f;
        float p2 = __shfl_down(v2.x, 1, 32); if (lane == 31) p2 = 0.f;
        float p3 = __shfl_down(v3.x, 1, 32); if (lane == 31) p3 = 0.f;

        float w00 = wtl[i * 9 + 0], w01 = wtl[i * 9 + 1], w02 = wtl[i * 9 + 2];
        float w10 = wtl[i * 9 + 3], w11 = wtl[i * 9 + 4], w12 = wtl[i * 9 + 5];
        float w20 = wtl[i * 9 + 6], w21 = wtl[i * 9 + 7], w22 = wtl[i * 9 + 8];

        // row A (y0): v0*ky0 + v1*ky1 + v2*ky2
        accA.x += w00 * m0   + w01 * v0.x + w02 * v0.y;
        accA.y += w00 * v0.x + w01 * v0.y + w02 * v0.z;
        accA.z += w00 * v0.y + w01 * v0.z + w02 * v0.w;
        accA.w += w00 * v0.z + w01 * v0.w + w02 * p0;
        accA.x += w10 * m1   + w11 * v1.x + w12 * v1.y;
        accA.y += w10 * v1.x + w11 * v1.y + w12 * v1.z;
        accA.z += w10 * v1.y + w11 * v1.z + w12 * v1.w;
        accA.w += w10 * v1.z + w11 * v1.w + w12 * p1;
        accA.x += w20 * m2v  + w21 * v2.x + w22 * v2.y;
        accA.y += w20 * v2.x + w21 * v2.y + w22 * v2.z;
        accA.z += w20 * v2.y + w21 * v2.z + w22 * v2.w;
        accA.w += w20 * v2.z + w21 * v2.w + w22 * p2;
        // row B (y0+1): v1*ky0 + v2*ky1 + v3*ky2
        accB.x += w00 * m1   + w01 * v1.x + w02 * v1.y;
        accB.y += w00 * v1.x + w01 * v1.y + w02 * v1.z;
        accB.z += w00 * v1.y + w01 * v1.z + w02 * v1.w;
        accB.w += w00 * v1.z + w01 * v1.w + w02 * p1;
        accB.x += w10 * m2v  + w11 * v2.x + w12 * v2.y;
        accB.y += w10 * v2.x + w11 * v2.y + w12 * v2.z;
        accB.z += w10 * v2.y + w11 * v2.z + w12 * v2.w;
        accB.w += w10 * v2.z + w11 * v2.w + w12 * p2;
        accB.x += w20 * m3   + w21 * v3.x + w22 * v3.y;
        accB.y += w20 * v3.x + w21 * v3.y + w22 * v3.z;
        accB.z += w20 * v3.y + w21 * v3.z + w22 * v3.w;
        accB.w += w20 * v3.z + w21 * v3.w + w22 * p3;

        // gating term: alpha_i * sh_i[y] * sw_i[x] * x_i[y,x]
        float asA = al[i] * shl[i * 16 + 2 * yg];
        float asB = al[i] * shl[i * 16 + 2 * yg + 1];
        float4 s4 = *(const float4*)(swl + i * 128 + x0);
        accA.x += asA * s4.x * v1.x;
        accA.y += asA * s4.y * v1.y;
        accA.z += asA * s4.z * v1.z;
        accA.w += asA * s4.w * v1.w;
        accB.x += asB * s4.x * v2.x;
        accB.y += asB * s4.y * v2.y;
        accB.z += asB * s4.z * v2.z;
        accB.w += asB * s4.w * v2.w;
    }

    float4 sgA, sgB;
    sgA.x = 1.f / (1.f + __expf(-accA.x));
    sgA.y = 1.f / (1.f + __expf(-accA.y));
    sgA.z = 1.f / (1.f + __expf(-accA.z));
    sgA.w = 1.f / (1.f + __expf(-accA.w));
    sgB.x = 1.f / (1.f + __expf(-accB.x));
    sgB.y = 1.f / (1.f + __expf(-accB.y));
    sgB.z = 1.f / (1.f + __expf(-accB.z));
    sgB.w = 1.f / (1.f + __expf(-accB.w));

    size_t ob = pbase + (size_t)y0 * 128 + x0;
#pragma unroll
    for (int c = 0; c < 8; ++c) {
        const float* bp = x + pbase + (size_t)c * 16384 + x0;
        float4 c1 = *(const float4*)(bp + y0 * 128);        // L2-hot reload
        float4 c2 = *(const float4*)(bp + (y0 + 1) * 128);
        float4 oA = { c1.x * sgA.x, c1.y * sgA.y, c1.z * sgA.z, c1.w * sgA.w };
        float4 oB = { c2.x * sgB.x, c2.y * sgB.y, c2.z * sgB.z, c2.w * sgB.w };
        *(float4*)(out + ob + (size_t)c * 16384)       = oA;
        *(float4*)(out + ob + (size_t)c * 16384 + 128) = oB;
    }
}

extern "C" void kernel_launch(void* const* d_in, const int* in_sizes, int n_in,
                              void* d_out, int out_size, void* d_ws, size_t ws_size,
                              hipStream_t stream) {
    (void)in_sizes; (void)n_in; (void)out_size; (void)ws_size;
    const float* x    = (const float*)d_in[0];
    const float* w1   = (const float*)d_in[1];
    const float* b1   = (const float*)d_in[2];
    const float* w3   = (const float*)d_in[3];
    const float* b3   = (const float*)d_in[4];
    const float* gn_w = (const float*)d_in[5];
    const float* gn_b = (const float*)d_in[6];
    float* out = (float*)d_out;
    float* ws  = (float*)d_ws;

    float* rowsum = ws;              // 2048*128
    float* colsum = ws + 262144;     // 2048*128
    float* sh     = ws + 524288;     // 2048*128
    float* sw     = ws + 786432;     // 2048*128
    float* alpha  = ws + 1048576;    // 2048
    float* beta   = ws + 1050624;    // 256
    float* wt     = ws + 1050880;    // 72

    hipLaunchKernelGGL(k1_sums, dim3(2048), dim3(256),  0, stream, x, rowsum, colsum);
    hipLaunchKernelGGL(k2_mid,  dim3(256),  dim3(1024), 0, stream, x, rowsum, colsum,
                       w1, b1, w3, b3, gn_w, gn_b, sh, sw, wt, alpha, beta);
    hipLaunchKernelGGL(k3_out,  dim3(2048), dim3(256),  0, stream, x, sh, sw,
                       alpha, beta, wt, out);
}